// Round 7
// baseline (114.573 us; speedup 1.0000x reference)
//
#include <hip/hip_runtime.h>

// C^4 for B independent 6x6 fp32 matrices — wave-pipelined (T14 async-STAGE).
// Block = 1 wave = 64 threads, owns a strip of 8 consecutive 64-matrix chunks.
// Single 9.2 KB LDS buffer (occupancy preserved vs R5); the NEXT chunk is
// prefetched into 9 f32x4 registers while the current chunk computes, so the
// wave never exposes HBM load latency except once per strip (1/8 amortized).
// Per iter t:
//   ds_write p -> LDS            (transpose-in; conflict-free b128)
//   issue loads(t+1) -> p        (nontemporal; in flight across compute)
//   lgkmcnt(0); compute C^4 from own 9 contiguous float4 (odd stride, cf)
//   write result to own region; lgkmcnt(0)
//   gather ds_read + nontemporal coalesced stores
// DS ops are in-order per wave (gather reads precede next iter's ds_write);
// compiler inserts precise vmcnt/lgkmcnt for the p-register hazards.
// No barriers anywhere. B % 64 == 0 for this problem; guarded anyway.

#define WPB   64   // threads per block = matrices per chunk
#define STRIP 8    // chunks per block

typedef float f32x4 __attribute__((ext_vector_type(4)));

__device__ __forceinline__ void pow4_regs(float a[36])
{
    float b[36];
#pragma unroll
    for (int i = 0; i < 6; ++i)
#pragma unroll
        for (int j = 0; j < 6; ++j) {
            float s = a[i * 6 + 0] * a[0 * 6 + j];
#pragma unroll
            for (int k = 1; k < 6; ++k)
                s = fmaf(a[i * 6 + k], a[k * 6 + j], s);
            b[i * 6 + j] = s;
        }
#pragma unroll
    for (int i = 0; i < 6; ++i)
#pragma unroll
        for (int j = 0; j < 6; ++j) {
            float s = b[i * 6 + 0] * b[0 * 6 + j];
#pragma unroll
            for (int k = 1; k < 6; ++k)
                s = fmaf(b[i * 6 + k], b[k * 6 + j], s);
            a[i * 6 + j] = s;
        }
}

__global__ __launch_bounds__(64, 3) void matpow4_wavepipe(
    const float* __restrict__ C, float* __restrict__ out, int nfull, int B)
{
    __shared__ f32x4 lds4[WPB * 9];   // 9216 B

    const int lane = threadIdx.x;
    const long long c0 = (long long)blockIdx.x * STRIP;

    const f32x4* __restrict__ srcAll = reinterpret_cast<const f32x4*>(C);
    f32x4* __restrict__ dstAll = reinterpret_cast<f32x4*>(out);

    if (c0 < nfull) {
        const int nc = (int)min((long long)STRIP, (long long)nfull - c0);

        f32x4 p[9];
        // prologue: load chunk c0 into regs
        {
            const f32x4* src = srcAll + (size_t)c0 * (WPB * 9);
#pragma unroll
            for (int k = 0; k < 9; ++k)
                p[k] = __builtin_nontemporal_load(src + k * WPB + lane);
        }

        for (int t = 0; t < nc; ++t) {
            // transpose-in: dense reg slices -> LDS (waits p's loads via
            // compiler-inserted vmcnt; conflict-free b128 writes)
#pragma unroll
            for (int k = 0; k < 9; ++k)
                lds4[k * WPB + lane] = p[k];

            // prefetch next chunk into p (WAR on p ordered vs the ds_writes
            // by the compiler; loads stay in flight across the compute)
            if (t + 1 < nc) {
                const f32x4* src = srcAll + (size_t)(c0 + t + 1) * (WPB * 9);
#pragma unroll
                for (int k = 0; k < 9; ++k)
                    p[k] = __builtin_nontemporal_load(src + k * WPB + lane);
            }

            asm volatile("s_waitcnt lgkmcnt(0)" ::: "memory");  // ds_writes done

            // compute: own matrix = 9 consecutive float4 at lds4[lane*9]
            {
                float a[36];
#pragma unroll
                for (int j = 0; j < 9; ++j) {
                    f32x4 v = lds4[lane * 9 + j];
                    a[4 * j + 0] = v.x;
                    a[4 * j + 1] = v.y;
                    a[4 * j + 2] = v.z;
                    a[4 * j + 3] = v.w;
                }
                pow4_regs(a);
#pragma unroll
                for (int j = 0; j < 9; ++j) {
                    f32x4 v;
                    v.x = a[4 * j + 0];
                    v.y = a[4 * j + 1];
                    v.z = a[4 * j + 2];
                    v.w = a[4 * j + 3];
                    lds4[lane * 9 + j] = v;
                }
            }
            asm volatile("s_waitcnt lgkmcnt(0)" ::: "memory");  // results visible

            // transpose-out: gather + coalesced nontemporal stores
            {
                f32x4* dst = dstAll + (size_t)(c0 + t) * (WPB * 9);
#pragma unroll
                for (int k = 0; k < 9; ++k) {
                    f32x4 v = lds4[k * WPB + lane];
                    __builtin_nontemporal_store(v, dst + k * WPB + lane);
                }
            }
            // next iter's ds_write is ordered after these gather ds_reads by
            // per-wave DS in-order execution; no barrier needed.
        }
    }

    // element tail (B % 64) — absent for this problem but kept for safety;
    // handled by the one block past the strip range.
    const long long tbase = (long long)nfull * WPB;
    if (c0 >= nfull && (c0 - STRIP < nfull || blockIdx.x == gridDim.x - 1)) {
        long long idx = tbase + lane;
        if (idx < B && (c0 == ((nfull + STRIP - 1) / STRIP) * (long long)STRIP
                        || blockIdx.x == gridDim.x - 1)) {
            const f32x4* src = srcAll + (size_t)idx * 9;
            float a[36];
#pragma unroll
            for (int j = 0; j < 9; ++j) {
                f32x4 v = src[j];
                a[4 * j + 0] = v.x;
                a[4 * j + 1] = v.y;
                a[4 * j + 2] = v.z;
                a[4 * j + 3] = v.w;
            }
            pow4_regs(a);
            f32x4* dst = dstAll + (size_t)idx * 9;
#pragma unroll
            for (int j = 0; j < 9; ++j) {
                f32x4 v;
                v.x = a[4 * j + 0];
                v.y = a[4 * j + 1];
                v.z = a[4 * j + 2];
                v.w = a[4 * j + 3];
                dst[j] = v;
            }
        }
    }
}

extern "C" void kernel_launch(void* const* d_in, const int* in_sizes, int n_in,
                              void* d_out, int out_size, void* d_ws, size_t ws_size,
                              hipStream_t stream)
{
    const float* C = (const float*)d_in[0];
    float* out = (float*)d_out;
    int B = in_sizes[0] / 36;

    int nfull = B / WPB;                       // full 64-matrix chunks
    int nstrip = (nfull + STRIP - 1) / STRIP;  // strip blocks
    int grid = nstrip + ((B % WPB) ? 1 : 0);   // + tail block if needed
    matpow4_wavepipe<<<grid, WPB, 0, stream>>>(C, out, nfull, B);
}